// Round 10
// baseline (468.102 us; speedup 1.0000x reference)
//
#include <hip/hip_runtime.h>
#include <hip/hip_cooperative_groups.h>
#include <hip/hip_fp16.h>
#include <math.h>

namespace cg = cooperative_groups;

// ---------------------------------------------------------------------------
// GAT 2-layer forward. N=50000, E=1.6M (+N self loops), F: 128 -> (4x32) -> 64.
// R2: CSR via two-pass bucket sort of packed (dst<<16|src) codes.
// R4: fp16-MFMA GEMMs + fused attention-dot epilogue; fp16 inter-stage.
// R5: LDS (exp,offset) exchange in aggregates.
// R7: 6 dispatches (232us); ~65us total inter-dispatch gap.
// R8 FAILED: 1024-thr mega-kernel -> 128-reg cap -> gemm spill -> 426us.
// R9 FAILED: cooperative tail grid hard-coded 1280 > runtime occupancy limit
//   (launch_bounds(256,5) -> 104 VGPR by granularity -> 4 blocks/CU -> max
//   1024) -> hipErrorCooperativeLaunchTooLarge, silently zero output.
// R10: tail grid clamped by hipOccupancyMaxActiveBlocksPerMultiprocessor
//   (host query, capture-safe); launch_bounds(256,4); non-cooperative
//   3-dispatch fallback if the cooperative launch is rejected.
// ---------------------------------------------------------------------------

#define NB_BUCKETS 256   // max coarse buckets (dst>>8); used = ceil(N/256)
#define BCAP 16384       // capacity per coarse bucket region (avg ~8448)

typedef _Float16 half8 __attribute__((ext_vector_type(8)));
typedef float    floatx4 __attribute__((ext_vector_type(4)));

struct f2 { float x, y; };

__device__ __forceinline__ unsigned short f2h_bits(float f) {
    return __half_as_ushort(__float2half(f));
}
__device__ __forceinline__ float h2f_lo(unsigned int u) {
    return __half2float(__ushort_as_half((unsigned short)(u & 0xFFFFu)));
}
__device__ __forceinline__ float h2f_hi(unsigned int u) {
    return __half2float(__ushort_as_half((unsigned short)(u >> 16)));
}

// ---------------------------------------------------------------------------
// splitA body (256 thr, R7-proven): block-aggregated split by dst>>8
// ---------------------------------------------------------------------------
__device__ void splitA_body(int bx, const int* __restrict__ eidx,
        unsigned int* __restrict__ tmp, int* __restrict__ coarse_fill,
        int E, int etot, int nb)
{
    __shared__ int hist[NB_BUCKETS];
    __shared__ int gb[NB_BUCKETS];
    __shared__ int cnt2[NB_BUCKETS];
    int t = threadIdx.x;
    if (t < nb) { hist[t] = 0; cnt2[t] = 0; }
    __syncthreads();

    unsigned int val[16];
    int bkt[16];
    int base = bx * 4096;
    #pragma unroll
    for (int i = 0; i < 16; i++) {
        int idx = base + i * 256 + t;
        if (idx < etot) {
            unsigned int s, d;
            if (idx < E) { s = (unsigned int)eidx[idx]; d = (unsigned int)eidx[E + idx]; }
            else         { s = (unsigned int)(idx - E); d = s; }
            val[i] = (d << 16) | s;
            bkt[i] = (int)(d >> 8);
            atomicAdd(&hist[bkt[i]], 1);
        } else {
            bkt[i] = -1;
        }
    }
    __syncthreads();
    if (t < nb) {
        int n = hist[t];
        gb[t] = (n > 0) ? atomicAdd(&coarse_fill[t], n) : 0;
    }
    __syncthreads();
    #pragma unroll
    for (int i = 0; i < 16; i++) {
        if (bkt[i] >= 0) {
            int loc = atomicAdd(&cnt2[bkt[i]], 1);
            tmp[(size_t)bkt[i] * BCAP + gb[bkt[i]] + loc] = val[i];
        }
    }
}

// ---------------------------------------------------------------------------
// GEMM (fp16 MFMA) + attention dots + fp16 payload. Bs passed in (16KB for
// NT=4, 32KB for NT=8). 256 thr = 4 waves x 16 rows.
// ---------------------------------------------------------------------------
template<int NT, int H, bool AF16>
__device__ void gemm_attn_body(_Float16* Bs, int bx,
        const void* __restrict__ Xv, const float* __restrict__ W,
        const float* __restrict__ att_s, const float* __restrict__ att_d,
        unsigned short* __restrict__ Hf16, float* __restrict__ as_,
        float* __restrict__ ad_, int M)
{
    constexpr int D = NT * 16;      // output width
    constexpr int C = D / H;        // channels per head

    int t = threadIdx.x;
    for (int idx = t; idx < 128 * D; idx += 256) {
        int k = idx / D;
        int n = idx - k * D;
        int nt = n >> 4, ks = k >> 5;
        int lane = (((k >> 3) & 3) << 4) | (n & 15);
        int j = k & 7;
        Bs[(((nt * 4 + ks) * 64 + lane) << 3) + j] = (_Float16)W[idx];
    }
    __syncthreads();

    int lane = t & 63;
    int wv = t >> 6;
    int quad = lane >> 4, colL = lane & 15;
    int row0 = bx * 64 + wv * 16;

    int arow = row0 + colL; if (arow > M - 1) arow = M - 1;
    half8 afrag[4];
    if constexpr (AF16) {
        const unsigned short* Xh = (const unsigned short*)Xv;
        #pragma unroll
        for (int ks = 0; ks < 4; ks++)
            afrag[ks] = *(const half8*)(const void*)(Xh + (size_t)arow * 128 + ks * 32 + quad * 8);
    } else {
        const float* Xf = (const float*)Xv;
        #pragma unroll
        for (int ks = 0; ks < 4; ks++) {
            const float* pa = Xf + (size_t)arow * 128 + ks * 32 + quad * 8;
            float4 a0 = *(const float4*)pa;
            float4 a1 = *(const float4*)(pa + 4);
            half8 f;
            f[0] = (_Float16)a0.x; f[1] = (_Float16)a0.y;
            f[2] = (_Float16)a0.z; f[3] = (_Float16)a0.w;
            f[4] = (_Float16)a1.x; f[5] = (_Float16)a1.y;
            f[6] = (_Float16)a1.z; f[7] = (_Float16)a1.w;
            afrag[ks] = f;
        }
    }

    floatx4 acc[NT];
    #pragma unroll
    for (int nt = 0; nt < NT; nt++) {
        floatx4 c = {0.f, 0.f, 0.f, 0.f};
        #pragma unroll
        for (int ks = 0; ks < 4; ks++) {
            half8 b = *(half8*)(void*)&Bs[(((nt * 4 + ks) * 64 + lane) << 3)];
            c = __builtin_amdgcn_mfma_f32_16x16x32_f16(afrag[ks], b, c, 0, 0, 0);
        }
        acc[nt] = c;
    }

    float atts[NT], attd[NT];
    #pragma unroll
    for (int nt = 0; nt < NT; nt++) {
        int ch = nt * 16 + colL;
        atts[nt] = att_s[ch];
        attd[nt] = att_d[ch];
    }
    float ps[H][4], pd[H][4];
    #pragma unroll
    for (int h = 0; h < H; h++)
        #pragma unroll
        for (int r = 0; r < 4; r++) { ps[h][r] = 0.f; pd[h][r] = 0.f; }
    #pragma unroll
    for (int nt = 0; nt < NT; nt++) {
        int h = (nt * 16) / C;
        #pragma unroll
        for (int r = 0; r < 4; r++) {
            ps[h][r] += acc[nt][r] * atts[nt];
            pd[h][r] += acc[nt][r] * attd[nt];
        }
    }
    #pragma unroll
    for (int h = 0; h < H; h++)
        #pragma unroll
        for (int r = 0; r < 4; r++)
            #pragma unroll
            for (int off = 1; off < 16; off <<= 1) {
                ps[h][r] += __shfl_xor(ps[h][r], off);
                pd[h][r] += __shfl_xor(pd[h][r], off);
            }
    if (colL < H) {
        #pragma unroll
        for (int r = 0; r < 4; r++) {
            int row = row0 + quad * 4 + r;
            if (row < M) {
                float vs, vd;
                if constexpr (H == 4) {
                    vs = colL == 0 ? ps[0][r] : colL == 1 ? ps[1][r] : colL == 2 ? ps[2][r] : ps[3][r];
                    vd = colL == 0 ? pd[0][r] : colL == 1 ? pd[1][r] : colL == 2 ? pd[2][r] : pd[3][r];
                } else {
                    vs = ps[0][r]; vd = pd[0][r];
                }
                as_[(size_t)row * H + colL] = vs;
                ad_[(size_t)row * H + colL] = vd;
            }
        }
    }

    #pragma unroll
    for (int r = 0; r < 4; r++) {
        int row = row0 + quad * 4 + r;
        if (row < M) {
            #pragma unroll
            for (int nt = 0; nt < NT; nt++)
                Hf16[(size_t)row * D + nt * 16 + colL] = f2h_bits(acc[nt][r]);
        }
    }
}

// ---------------------------------------------------------------------------
// Fat kernel (R7-proven, unconstrained regs): gemm_attn1 || splitA
// ---------------------------------------------------------------------------
__global__ __launch_bounds__(256) void build_and_gemm1_kernel(
        const int* __restrict__ eidx, unsigned int* __restrict__ tmp,
        int* __restrict__ cfill, int E, int etot, int nb,
        const float* __restrict__ x, const float* __restrict__ W1,
        const float* __restrict__ att_s, const float* __restrict__ att_d,
        unsigned short* __restrict__ h1f16, float* __restrict__ as1,
        float* __restrict__ ad1, int M, int nbG)
{
    if ((int)blockIdx.x < nbG) {
        __shared__ _Float16 Bs[8 * 4 * 64 * 8];
        gemm_attn_body<8, 4, false>(Bs, (int)blockIdx.x, x, W1, att_s, att_d,
                                    h1f16, as1, ad1, M);
    } else {
        splitA_body((int)blockIdx.x - nbG, eidx, tmp, cfill, E, etot, nb);
    }
}

// ---------------------------------------------------------------------------
// passB (R7-proven, 1024 thr): inline scan + counting sort -> col + rowp
// ---------------------------------------------------------------------------
__global__ __launch_bounds__(1024) void passB_kernel(const unsigned int* __restrict__ tmp,
        const int* __restrict__ cfill, int* __restrict__ col,
        int* __restrict__ rowp, int N_, int nb, int etot)
{
    __shared__ int sd[256];
    __shared__ int hist2[256];
    __shared__ int scn[256];
    __shared__ int off2[256];
    int b = blockIdx.x;
    int t = threadIdx.x;

    if (t < 256) sd[t] = (t < nb) ? cfill[t] : 0;
    __syncthreads();
    for (int off = 1; off < 256; off <<= 1) {
        int y = 0;
        if (t < 256 && t >= off) y = sd[t - off];
        __syncthreads();
        if (t < 256) sd[t] += y;
        __syncthreads();
    }
    int base = sd[b] - cfill[b];     // exclusive prefix for this bucket
    int n = cfill[b];
    const unsigned int* seg = tmp + (size_t)b * BCAP;

    if (t < 256) hist2[t] = 0;
    __syncthreads();
    for (int i = t; i < n; i += 1024) {
        unsigned int v = seg[i];
        atomicAdd(&hist2[(v >> 16) & 255], 1);
    }
    __syncthreads();
    int myc = (t < 256) ? hist2[t] : 0;
    if (t < 256) scn[t] = myc;
    __syncthreads();
    for (int off = 1; off < 256; off <<= 1) {
        int y = 0;
        if (t < 256 && t >= off) y = scn[t - off];
        __syncthreads();
        if (t < 256) scn[t] += y;
        __syncthreads();
    }
    if (t < 256) {
        int excl = scn[t] - myc;
        off2[t] = excl;
        int node = b * 256 + t;
        if (node <= N_) rowp[node] = base + excl;
        if (node == N_) rowp[N_] = etot;
    }
    __syncthreads();
    for (int i = t; i < n; i += 1024) {
        unsigned int v = seg[i];
        int bin = (v >> 16) & 255;
        int loc = atomicAdd(&off2[bin], 1);
        col[base + loc] = (int)(v & 0xFFFFu);
    }
}

// ---------------------------------------------------------------------------
// Aggregate body (R5/R7-proven math): one wave per dst node, exs passed in.
// ---------------------------------------------------------------------------
template<int H, int C, bool ELU_, bool OUTF16>
__device__ void agg_body(f2* exs, int vb,
        const int* __restrict__ row_ptr, const int* __restrict__ col_src,
        const unsigned short* __restrict__ payload, const float* __restrict__ asv,
        const float* __restrict__ adv, const float* __restrict__ bias,
        void* __restrict__ outv, int nnodes)
{
    constexpr int D = H * C;
    constexpr int CPL = 8;            // channels per lane (uint4 of halves)
    constexpr int LPE = D / CPL;      // lanes per edge: 16 (L1) or 8 (L2)
    constexpr int EPI = 64 / LPE;     // edges per inner iter: 4 or 8
    int wave = threadIdx.x >> 6, lane = threadIdx.x & 63;
    int node = vb * 4 + wave;
    if (node >= nnodes) return;
    int start = row_ptr[node];
    int deg   = row_ptr[node + 1] - start;   // >= 1 (self loop)
    int li  = lane & (LPE - 1);
    int sub = lane / LPE;
    int myh = (li * CPL) / C;
    int lane_off = li * 16;                  // byte offset within a row
    f2* exw = exs + (size_t)wave * H * 65;

    float adh[H];
    #pragma unroll
    for (int h = 0; h < H; h++) adh[h] = adv[(size_t)node * H + h];

    float m[H];
    #pragma unroll
    for (int h = 0; h < H; h++) m[h] = -3.0e38f;
    float acc[CPL];
    #pragma unroll
    for (int k = 0; k < CPL; k++) acc[k] = 0.f;
    float sacc = 0.f;
    const char* pb = (const char*)payload;

    for (int c0 = 0; c0 < deg; c0 += 64) {
        int cnt = deg - c0; if (cnt > 64) cnt = 64;
        int idx = c0 + lane;
        int svec = 0;
        float e[H];
        if (idx < deg) {
            svec = col_src[start + idx];
            if constexpr (H == 4) {
                float4 av = *(const float4*)(asv + (size_t)svec * 4);
                float t0 = av.x + adh[0], t1 = av.y + adh[1];
                float t2 = av.z + adh[2], t3 = av.w + adh[3];
                e[0] = fmaxf(t0, 0.2f * t0); e[1] = fmaxf(t1, 0.2f * t1);
                e[2] = fmaxf(t2, 0.2f * t2); e[3] = fmaxf(t3, 0.2f * t3);
            } else {
                float tt = asv[svec] + adh[0];
                e[0] = fmaxf(tt, 0.2f * tt);
            }
        } else {
            #pragma unroll
            for (int h = 0; h < H; h++) e[h] = -3.0e38f;
        }
        float nm[H];
        #pragma unroll
        for (int h = 0; h < H; h++) {
            float v = e[h];
            #pragma unroll
            for (int off = 32; off >= 1; off >>= 1)
                v = fmaxf(v, __shfl_xor(v, off));
            nm[h] = fmaxf(m[h], v);
        }
        float sc = __expf(m[myh] - nm[myh]);  // first chunk: 0
        sacc *= sc;
        #pragma unroll
        for (int k = 0; k < CPL; k++) acc[k] *= sc;
        #pragma unroll
        for (int h = 0; h < H; h++) m[h] = nm[h];

        unsigned int boff = (unsigned int)svec * (unsigned int)(D * 2);
        float boff_f = __uint_as_float(boff);
        #pragma unroll
        for (int h = 0; h < H; h++) {
            float ex = (idx < deg) ? __expf(e[h] - m[h]) : 0.f;
            exw[h * 65 + lane].x = ex;
            exw[h * 65 + lane].y = boff_f;
        }

        int iters = (cnt + EPI - 1) / EPI;
        #pragma unroll 2
        for (int it = 0; it < iters; it++) {
            int el = it * EPI + sub;
            f2 v = exw[myh * 65 + el];
            float exj = v.x;
            unsigned int off = __float_as_uint(v.y);
            uint4 hv = *(const uint4*)(const void*)(pb + off + lane_off);
            sacc += exj;
            acc[0] = fmaf(h2f_lo(hv.x), exj, acc[0]);
            acc[1] = fmaf(h2f_hi(hv.x), exj, acc[1]);
            acc[2] = fmaf(h2f_lo(hv.y), exj, acc[2]);
            acc[3] = fmaf(h2f_hi(hv.y), exj, acc[3]);
            acc[4] = fmaf(h2f_lo(hv.z), exj, acc[4]);
            acc[5] = fmaf(h2f_hi(hv.z), exj, acc[5]);
            acc[6] = fmaf(h2f_lo(hv.w), exj, acc[6]);
            acc[7] = fmaf(h2f_hi(hv.w), exj, acc[7]);
        }
    }

    #pragma unroll
    for (int off = LPE; off < 64; off <<= 1) {
        sacc += __shfl_xor(sacc, off);
        #pragma unroll
        for (int k = 0; k < CPL; k++) acc[k] += __shfl_xor(acc[k], off);
    }
    if (sub == 0) {
        float inv = 1.f / (sacc + 1e-16f);
        int ch = li * CPL;
        float r[CPL];
        #pragma unroll
        for (int k = 0; k < CPL; k++) {
            r[k] = acc[k] * inv + bias[ch + k];
            if (ELU_) r[k] = r[k] > 0.f ? r[k] : (__expf(r[k]) - 1.f);
        }
        if constexpr (OUTF16) {
            unsigned short* o = (unsigned short*)outv;
            unsigned int w0 = (unsigned int)f2h_bits(r[0]) | ((unsigned int)f2h_bits(r[1]) << 16);
            unsigned int w1 = (unsigned int)f2h_bits(r[2]) | ((unsigned int)f2h_bits(r[3]) << 16);
            unsigned int w2 = (unsigned int)f2h_bits(r[4]) | ((unsigned int)f2h_bits(r[5]) << 16);
            unsigned int w3 = (unsigned int)f2h_bits(r[6]) | ((unsigned int)f2h_bits(r[7]) << 16);
            uint4 q = { w0, w1, w2, w3 };
            *(uint4*)(void*)(o + (size_t)node * D + ch) = q;
        } else {
            float* o = (float*)outv;
            float4 w0 = { r[0], r[1], r[2], r[3] };
            float4 w1 = { r[4], r[5], r[6], r[7] };
            *(float4*)(o + (size_t)node * D + ch) = w0;
            *(float4*)(o + (size_t)node * D + ch + 4) = w1;
        }
    }
}

// ---------------------------------------------------------------------------
// Cooperative tail: agg1 -> gemm2 -> agg2 in one kernel (removes 2 gaps).
// Grid clamped by occupancy query at launch (R9 lesson).
// ---------------------------------------------------------------------------
struct TailParams {
    const int* rowp; const int* colidx;
    const unsigned short* h1f16;
    const float* as1; const float* ad1; const float* bias1;
    unsigned short* hx16;
    const float* W2; const float* att_s2; const float* att_d2; const float* bias2;
    unsigned short* h2f16;
    float* as2; float* ad2;
    float* out;
    int N, nbagg, nbG2;
};

#define TAIL_SM 16640   // max(Bs NT=4: 16384 B, exs 4*4*65*8 = 8320 B)

__global__ __launch_bounds__(256, 4) void tail_mega_kernel(TailParams p)
{
    __shared__ __align__(16) char sm[TAIL_SM];
    cg::grid_group grid = cg::this_grid();
    const int GB = (int)gridDim.x;

    // P3: layer-1 aggregate (4 nodes / virtual block)
    for (int vb = (int)blockIdx.x; vb < p.nbagg; vb += GB)
        agg_body<4, 32, true, true>((f2*)sm, vb, p.rowp, p.colidx, p.h1f16,
                                    p.as1, p.ad1, p.bias1, p.hx16, p.N);
    grid.sync();

    // P4: layer-2 gemm+attn (64 rows / virtual block)
    for (int vb = (int)blockIdx.x; vb < p.nbG2; vb += GB) {
        __syncthreads();   // protect Bs reuse across loop iterations
        gemm_attn_body<4, 1, true>((_Float16*)sm, vb, p.hx16, p.W2,
                                   p.att_s2, p.att_d2, p.h2f16, p.as2, p.ad2, p.N);
    }
    grid.sync();

    // P5: layer-2 aggregate -> fp32 out
    for (int vb = (int)blockIdx.x; vb < p.nbagg; vb += GB)
        agg_body<1, 64, false, false>((f2*)sm, vb, p.rowp, p.colidx, p.h2f16,
                                      p.as2, p.ad2, p.bias2, p.out, p.N);
}

// ---- non-cooperative fallbacks (same math; used only if coop launch fails) --
__global__ __launch_bounds__(256) void agg1_kernel(TailParams p)
{
    __shared__ __align__(16) char sm[8320];
    agg_body<4, 32, true, true>((f2*)sm, (int)blockIdx.x, p.rowp, p.colidx,
                                p.h1f16, p.as1, p.ad1, p.bias1, p.hx16, p.N);
}
__global__ __launch_bounds__(256) void gemm2_kernel(TailParams p)
{
    __shared__ _Float16 Bs[4 * 4 * 64 * 8];
    gemm_attn_body<4, 1, true>(Bs, (int)blockIdx.x, p.hx16, p.W2,
                               p.att_s2, p.att_d2, p.h2f16, p.as2, p.ad2, p.N);
}
__global__ __launch_bounds__(256) void agg2_kernel(TailParams p)
{
    __shared__ __align__(16) char sm[8320];
    agg_body<1, 64, false, false>((f2*)sm, (int)blockIdx.x, p.rowp, p.colidx,
                                  p.h2f16, p.as2, p.ad2, p.bias2, p.out, p.N);
}

// ---------------------------------------------------------------------------
extern "C" void kernel_launch(void* const* d_in, const int* in_sizes, int n_in,
                              void* d_out, int out_size, void* d_ws, size_t ws_size,
                              hipStream_t stream)
{
    const float* x        = (const float*)d_in[0];
    const int*   eidx     = (const int*)  d_in[1];
    const float* W1       = (const float*)d_in[2];
    const float* att_src1 = (const float*)d_in[3];
    const float* att_dst1 = (const float*)d_in[4];
    const float* bias1    = (const float*)d_in[5];
    const float* W2       = (const float*)d_in[6];
    const float* att_src2 = (const float*)d_in[7];
    const float* att_dst2 = (const float*)d_in[8];
    const float* bias2    = (const float*)d_in[9];
    float* out = (float*)d_out;

    const int N_ = in_sizes[0] / 128;
    const int E_ = in_sizes[1] / 2;
    const int ET = E_ + N_;
    const int NB = (N_ + 255) / 256;

    char* p = (char*)d_ws;
    auto alloc = [&](size_t bytes) {
        void* r = (void*)p;
        p += ((bytes + 255) / 256) * 256;
        return r;
    };
    int* rowp  = (int*)alloc((size_t)(N_ + 1) * 4);
    int* cfill = (int*)alloc((size_t)NB_BUCKETS * 4);
    int* colidx = (int*)alloc((size_t)ET * 4);
    unsigned int*   tmp   = (unsigned int*)alloc((size_t)NB_BUCKETS * BCAP * 4);
    // h1f16 must not alias tmp: gemm1 runs concurrently with splitA
    unsigned short* h1f16 = (unsigned short*)alloc((size_t)N_ * 128 * 2);
    unsigned short* hx16  = (unsigned short*)alloc((size_t)N_ * 128 * 2);
    unsigned short* h2f16 = (unsigned short*)alloc((size_t)N_ * 64 * 2);
    float* as1 = (float*)alloc((size_t)N_ * 4 * 4);
    float* ad1 = (float*)alloc((size_t)N_ * 4 * 4);
    float* as2 = (float*)alloc((size_t)N_ * 4);
    float* ad2 = (float*)alloc((size_t)N_ * 4);
    (void)ws_size; (void)n_in; (void)out_size;

    const int nbG = (N_ + 63) / 64;          // gemm blocks (782)
    const int nbA = (ET + 4095) / 4096;      // splitA blocks (403)

    // 1) zero bucket counters
    hipMemsetAsync(cfill, 0, (size_t)NB_BUCKETS * 4, stream);
    // 2) fat kernel: gemm_attn1 (MFMA) || splitA (LDS/mem) — independent
    build_and_gemm1_kernel<<<nbG + nbA, 256, 0, stream>>>(
        eidx, tmp, cfill, E_, ET, NB,
        x, W1, att_src1, att_dst1, h1f16, as1, ad1, N_, nbG);
    // 3) counting sort per bucket (inline scan) -> col + rowp
    passB_kernel<<<NB, 1024, 0, stream>>>(tmp, cfill, colidx, rowp, N_, NB, ET);

    // 4) cooperative tail: agg1 -> gemm2 -> agg2 (grid clamped by occupancy)
    TailParams tp;
    tp.rowp = rowp; tp.colidx = colidx;
    tp.h1f16 = h1f16; tp.as1 = as1; tp.ad1 = ad1; tp.bias1 = bias1;
    tp.hx16 = hx16;
    tp.W2 = W2; tp.att_s2 = att_src2; tp.att_d2 = att_dst2; tp.bias2 = bias2;
    tp.h2f16 = h2f16; tp.as2 = as2; tp.ad2 = ad2;
    tp.out = out;
    tp.N = N_;
    tp.nbagg = (N_ + 3) / 4;   // 12500
    tp.nbG2  = nbG;            // 782

    int occ = 0;
    hipError_t oerr = hipOccupancyMaxActiveBlocksPerMultiprocessor(
        &occ, (const void*)tail_mega_kernel, 256, 0);
    bool coop_ok = false;
    if (oerr == hipSuccess && occ > 0) {
        int grid = occ * 256;              // guaranteed co-resident on 256 CUs
        if (grid > 1280) grid = 1280;      // no benefit beyond 5 blocks/CU
        void* kargs[] = { &tp };
        hipError_t lerr = hipLaunchCooperativeKernel(
            (const void*)tail_mega_kernel, dim3(grid), dim3(256), kargs, 0, stream);
        coop_ok = (lerr == hipSuccess);
    }
    if (!coop_ok) {
        // deterministic fallback: identical math, three dispatches (R7 path)
        agg1_kernel<<<tp.nbagg, 256, 0, stream>>>(tp);
        gemm2_kernel<<<tp.nbG2, 256, 0, stream>>>(tp);
        agg2_kernel<<<tp.nbagg, 256, 0, stream>>>(tp);
    }
}

// Round 11
// 467.548 us; speedup vs baseline: 1.0012x; 1.0012x over previous
//
#include <hip/hip_runtime.h>
#include <hip/hip_cooperative_groups.h>
#include <hip/hip_fp16.h>
#include <math.h>

namespace cg = cooperative_groups;

// ---------------------------------------------------------------------------
// GAT 2-layer forward. N=50000, E=1.6M (+N self loops), F: 128 -> (4x32) -> 64.
// R2: CSR via two-pass bucket sort of packed (dst<<16|src) codes.
// R4: fp16-MFMA GEMMs + fused attention-dot epilogue; fp16 inter-stage.
// R5: LDS (exp,offset) exchange in aggregates.
// R7: 6 dispatches, 232us; ~55-65us inter-dispatch gap.
// R8/R10 FAILED: fused kernels compiled to 64/40 VGPRs — the backend's
//   occupancy heuristic squeezes registers despite launch_bounds CAP,
//   killing the agg gather pipeline (1 outstanding load/wave -> latency
//   serial, VALU 13%). Lesson: pin occupancy with amdgpu_waves_per_eu(max),
//   which makes sub-cap register squeezing pointless to the allocator.
// R11: R10 structure + waves_per_eu(2,4) pin on the cooperative tail;
//   single-b64 LDS exchange store; occupancy-clamped grid; R7 fallback.
// ---------------------------------------------------------------------------

#define NB_BUCKETS 256   // max coarse buckets (dst>>8); used = ceil(N/256)
#define BCAP 16384       // capacity per coarse bucket region (avg ~8448)

typedef _Float16 half8 __attribute__((ext_vector_type(8)));
typedef float    floatx4 __attribute__((ext_vector_type(4)));

struct f2 { float x, y; };

__device__ __forceinline__ unsigned short f2h_bits(float f) {
    return __half_as_ushort(__float2half(f));
}
__device__ __forceinline__ float h2f_lo(unsigned int u) {
    return __half2float(__ushort_as_half((unsigned short)(u & 0xFFFFu)));
}
__device__ __forceinline__ float h2f_hi(unsigned int u) {
    return __half2float(__ushort_as_half((unsigned short)(u >> 16)));
}

// ---------------------------------------------------------------------------
// splitA body (256 thr, R7-proven): block-aggregated split by dst>>8
// ---------------------------------------------------------------------------
__device__ void splitA_body(int bx, const int* __restrict__ eidx,
        unsigned int* __restrict__ tmp, int* __restrict__ coarse_fill,
        int E, int etot, int nb)
{
    __shared__ int hist[NB_BUCKETS];
    __shared__ int gb[NB_BUCKETS];
    __shared__ int cnt2[NB_BUCKETS];
    int t = threadIdx.x;
    if (t < nb) { hist[t] = 0; cnt2[t] = 0; }
    __syncthreads();

    unsigned int val[16];
    int bkt[16];
    int base = bx * 4096;
    #pragma unroll
    for (int i = 0; i < 16; i++) {
        int idx = base + i * 256 + t;
        if (idx < etot) {
            unsigned int s, d;
            if (idx < E) { s = (unsigned int)eidx[idx]; d = (unsigned int)eidx[E + idx]; }
            else         { s = (unsigned int)(idx - E); d = s; }
            val[i] = (d << 16) | s;
            bkt[i] = (int)(d >> 8);
            atomicAdd(&hist[bkt[i]], 1);
        } else {
            bkt[i] = -1;
        }
    }
    __syncthreads();
    if (t < nb) {
        int n = hist[t];
        gb[t] = (n > 0) ? atomicAdd(&coarse_fill[t], n) : 0;
    }
    __syncthreads();
    #pragma unroll
    for (int i = 0; i < 16; i++) {
        if (bkt[i] >= 0) {
            int loc = atomicAdd(&cnt2[bkt[i]], 1);
            tmp[(size_t)bkt[i] * BCAP + gb[bkt[i]] + loc] = val[i];
        }
    }
}

// ---------------------------------------------------------------------------
// GEMM (fp16 MFMA) + attention dots + fp16 payload. Bs passed in (16KB for
// NT=4, 32KB for NT=8). 256 thr = 4 waves x 16 rows.
// ---------------------------------------------------------------------------
template<int NT, int H, bool AF16>
__device__ void gemm_attn_body(_Float16* Bs, int bx,
        const void* __restrict__ Xv, const float* __restrict__ W,
        const float* __restrict__ att_s, const float* __restrict__ att_d,
        unsigned short* __restrict__ Hf16, float* __restrict__ as_,
        float* __restrict__ ad_, int M)
{
    constexpr int D = NT * 16;      // output width
    constexpr int C = D / H;        // channels per head

    int t = threadIdx.x;
    for (int idx = t; idx < 128 * D; idx += 256) {
        int k = idx / D;
        int n = idx - k * D;
        int nt = n >> 4, ks = k >> 5;
        int lane = (((k >> 3) & 3) << 4) | (n & 15);
        int j = k & 7;
        Bs[(((nt * 4 + ks) * 64 + lane) << 3) + j] = (_Float16)W[idx];
    }
    __syncthreads();

    int lane = t & 63;
    int wv = t >> 6;
    int quad = lane >> 4, colL = lane & 15;
    int row0 = bx * 64 + wv * 16;

    int arow = row0 + colL; if (arow > M - 1) arow = M - 1;
    half8 afrag[4];
    if constexpr (AF16) {
        const unsigned short* Xh = (const unsigned short*)Xv;
        #pragma unroll
        for (int ks = 0; ks < 4; ks++)
            afrag[ks] = *(const half8*)(const void*)(Xh + (size_t)arow * 128 + ks * 32 + quad * 8);
    } else {
        const float* Xf = (const float*)Xv;
        #pragma unroll
        for (int ks = 0; ks < 4; ks++) {
            const float* pa = Xf + (size_t)arow * 128 + ks * 32 + quad * 8;
            float4 a0 = *(const float4*)pa;
            float4 a1 = *(const float4*)(pa + 4);
            half8 f;
            f[0] = (_Float16)a0.x; f[1] = (_Float16)a0.y;
            f[2] = (_Float16)a0.z; f[3] = (_Float16)a0.w;
            f[4] = (_Float16)a1.x; f[5] = (_Float16)a1.y;
            f[6] = (_Float16)a1.z; f[7] = (_Float16)a1.w;
            afrag[ks] = f;
        }
    }

    floatx4 acc[NT];
    #pragma unroll
    for (int nt = 0; nt < NT; nt++) {
        floatx4 c = {0.f, 0.f, 0.f, 0.f};
        #pragma unroll
        for (int ks = 0; ks < 4; ks++) {
            half8 b = *(half8*)(void*)&Bs[(((nt * 4 + ks) * 64 + lane) << 3)];
            c = __builtin_amdgcn_mfma_f32_16x16x32_f16(afrag[ks], b, c, 0, 0, 0);
        }
        acc[nt] = c;
    }

    float atts[NT], attd[NT];
    #pragma unroll
    for (int nt = 0; nt < NT; nt++) {
        int ch = nt * 16 + colL;
        atts[nt] = att_s[ch];
        attd[nt] = att_d[ch];
    }
    float ps[H][4], pd[H][4];
    #pragma unroll
    for (int h = 0; h < H; h++)
        #pragma unroll
        for (int r = 0; r < 4; r++) { ps[h][r] = 0.f; pd[h][r] = 0.f; }
    #pragma unroll
    for (int nt = 0; nt < NT; nt++) {
        int h = (nt * 16) / C;
        #pragma unroll
        for (int r = 0; r < 4; r++) {
            ps[h][r] += acc[nt][r] * atts[nt];
            pd[h][r] += acc[nt][r] * attd[nt];
        }
    }
    #pragma unroll
    for (int h = 0; h < H; h++)
        #pragma unroll
        for (int r = 0; r < 4; r++)
            #pragma unroll
            for (int off = 1; off < 16; off <<= 1) {
                ps[h][r] += __shfl_xor(ps[h][r], off);
                pd[h][r] += __shfl_xor(pd[h][r], off);
            }
    if (colL < H) {
        #pragma unroll
        for (int r = 0; r < 4; r++) {
            int row = row0 + quad * 4 + r;
            if (row < M) {
                float vs, vd;
                if constexpr (H == 4) {
                    vs = colL == 0 ? ps[0][r] : colL == 1 ? ps[1][r] : colL == 2 ? ps[2][r] : ps[3][r];
                    vd = colL == 0 ? pd[0][r] : colL == 1 ? pd[1][r] : colL == 2 ? pd[2][r] : pd[3][r];
                } else {
                    vs = ps[0][r]; vd = pd[0][r];
                }
                as_[(size_t)row * H + colL] = vs;
                ad_[(size_t)row * H + colL] = vd;
            }
        }
    }

    #pragma unroll
    for (int r = 0; r < 4; r++) {
        int row = row0 + quad * 4 + r;
        if (row < M) {
            #pragma unroll
            for (int nt = 0; nt < NT; nt++)
                Hf16[(size_t)row * D + nt * 16 + colL] = f2h_bits(acc[nt][r]);
        }
    }
}

// ---------------------------------------------------------------------------
// Fat kernel (R7-proven, unconstrained regs): gemm_attn1 || splitA
// ---------------------------------------------------------------------------
__global__ __launch_bounds__(256) void build_and_gemm1_kernel(
        const int* __restrict__ eidx, unsigned int* __restrict__ tmp,
        int* __restrict__ cfill, int E, int etot, int nb,
        const float* __restrict__ x, const float* __restrict__ W1,
        const float* __restrict__ att_s, const float* __restrict__ att_d,
        unsigned short* __restrict__ h1f16, float* __restrict__ as1,
        float* __restrict__ ad1, int M, int nbG)
{
    if ((int)blockIdx.x < nbG) {
        __shared__ _Float16 Bs[8 * 4 * 64 * 8];
        gemm_attn_body<8, 4, false>(Bs, (int)blockIdx.x, x, W1, att_s, att_d,
                                    h1f16, as1, ad1, M);
    } else {
        splitA_body((int)blockIdx.x - nbG, eidx, tmp, cfill, E, etot, nb);
    }
}

// ---------------------------------------------------------------------------
// passB (R7-proven, 1024 thr): inline scan + counting sort -> col + rowp
// ---------------------------------------------------------------------------
__global__ __launch_bounds__(1024) void passB_kernel(const unsigned int* __restrict__ tmp,
        const int* __restrict__ cfill, int* __restrict__ col,
        int* __restrict__ rowp, int N_, int nb, int etot)
{
    __shared__ int sd[256];
    __shared__ int hist2[256];
    __shared__ int scn[256];
    __shared__ int off2[256];
    int b = blockIdx.x;
    int t = threadIdx.x;

    if (t < 256) sd[t] = (t < nb) ? cfill[t] : 0;
    __syncthreads();
    for (int off = 1; off < 256; off <<= 1) {
        int y = 0;
        if (t < 256 && t >= off) y = sd[t - off];
        __syncthreads();
        if (t < 256) sd[t] += y;
        __syncthreads();
    }
    int base = sd[b] - cfill[b];     // exclusive prefix for this bucket
    int n = cfill[b];
    const unsigned int* seg = tmp + (size_t)b * BCAP;

    if (t < 256) hist2[t] = 0;
    __syncthreads();
    for (int i = t; i < n; i += 1024) {
        unsigned int v = seg[i];
        atomicAdd(&hist2[(v >> 16) & 255], 1);
    }
    __syncthreads();
    int myc = (t < 256) ? hist2[t] : 0;
    if (t < 256) scn[t] = myc;
    __syncthreads();
    for (int off = 1; off < 256; off <<= 1) {
        int y = 0;
        if (t < 256 && t >= off) y = scn[t - off];
        __syncthreads();
        if (t < 256) scn[t] += y;
        __syncthreads();
    }
    if (t < 256) {
        int excl = scn[t] - myc;
        off2[t] = excl;
        int node = b * 256 + t;
        if (node <= N_) rowp[node] = base + excl;
        if (node == N_) rowp[N_] = etot;
    }
    __syncthreads();
    for (int i = t; i < n; i += 1024) {
        unsigned int v = seg[i];
        int bin = (v >> 16) & 255;
        int loc = atomicAdd(&off2[bin], 1);
        col[base + loc] = (int)(v & 0xFFFFu);
    }
}

// ---------------------------------------------------------------------------
// Aggregate body (R5/R7-proven math): one wave per dst node, exs passed in.
// ---------------------------------------------------------------------------
template<int H, int C, bool ELU_, bool OUTF16>
__device__ void agg_body(f2* exs, int vb,
        const int* __restrict__ row_ptr, const int* __restrict__ col_src,
        const unsigned short* __restrict__ payload, const float* __restrict__ asv,
        const float* __restrict__ adv, const float* __restrict__ bias,
        void* __restrict__ outv, int nnodes)
{
    constexpr int D = H * C;
    constexpr int CPL = 8;            // channels per lane (uint4 of halves)
    constexpr int LPE = D / CPL;      // lanes per edge: 16 (L1) or 8 (L2)
    constexpr int EPI = 64 / LPE;     // edges per inner iter: 4 or 8
    int wave = threadIdx.x >> 6, lane = threadIdx.x & 63;
    int node = vb * 4 + wave;
    if (node >= nnodes) return;
    int start = row_ptr[node];
    int deg   = row_ptr[node + 1] - start;   // >= 1 (self loop)
    int li  = lane & (LPE - 1);
    int sub = lane / LPE;
    int myh = (li * CPL) / C;
    int lane_off = li * 16;                  // byte offset within a row
    f2* exw = exs + (size_t)wave * H * 65;

    float adh[H];
    #pragma unroll
    for (int h = 0; h < H; h++) adh[h] = adv[(size_t)node * H + h];

    float m[H];
    #pragma unroll
    for (int h = 0; h < H; h++) m[h] = -3.0e38f;
    float acc[CPL];
    #pragma unroll
    for (int k = 0; k < CPL; k++) acc[k] = 0.f;
    float sacc = 0.f;
    const char* pb = (const char*)payload;

    for (int c0 = 0; c0 < deg; c0 += 64) {
        int cnt = deg - c0; if (cnt > 64) cnt = 64;
        int idx = c0 + lane;
        int svec = 0;
        float e[H];
        if (idx < deg) {
            svec = col_src[start + idx];
            if constexpr (H == 4) {
                float4 av = *(const float4*)(asv + (size_t)svec * 4);
                float t0 = av.x + adh[0], t1 = av.y + adh[1];
                float t2 = av.z + adh[2], t3 = av.w + adh[3];
                e[0] = fmaxf(t0, 0.2f * t0); e[1] = fmaxf(t1, 0.2f * t1);
                e[2] = fmaxf(t2, 0.2f * t2); e[3] = fmaxf(t3, 0.2f * t3);
            } else {
                float tt = asv[svec] + adh[0];
                e[0] = fmaxf(tt, 0.2f * tt);
            }
        } else {
            #pragma unroll
            for (int h = 0; h < H; h++) e[h] = -3.0e38f;
        }
        float nm[H];
        #pragma unroll
        for (int h = 0; h < H; h++) {
            float v = e[h];
            #pragma unroll
            for (int off = 32; off >= 1; off >>= 1)
                v = fmaxf(v, __shfl_xor(v, off));
            nm[h] = fmaxf(m[h], v);
        }
        float sc = __expf(m[myh] - nm[myh]);  // first chunk: 0
        sacc *= sc;
        #pragma unroll
        for (int k = 0; k < CPL; k++) acc[k] *= sc;
        #pragma unroll
        for (int h = 0; h < H; h++) m[h] = nm[h];

        unsigned int boff = (unsigned int)svec * (unsigned int)(D * 2);
        float boff_f = __uint_as_float(boff);
        #pragma unroll
        for (int h = 0; h < H; h++) {
            float ex = (idx < deg) ? __expf(e[h] - m[h]) : 0.f;
            f2 wr; wr.x = ex; wr.y = boff_f;
            exw[h * 65 + lane] = wr;          // single b64 store
        }

        int iters = (cnt + EPI - 1) / EPI;
        #pragma unroll 2
        for (int it = 0; it < iters; it++) {
            int el = it * EPI + sub;
            f2 v = exw[myh * 65 + el];
            float exj = v.x;
            unsigned int off = __float_as_uint(v.y);
            uint4 hv = *(const uint4*)(const void*)(pb + off + lane_off);
            sacc += exj;
            acc[0] = fmaf(h2f_lo(hv.x), exj, acc[0]);
            acc[1] = fmaf(h2f_hi(hv.x), exj, acc[1]);
            acc[2] = fmaf(h2f_lo(hv.y), exj, acc[2]);
            acc[3] = fmaf(h2f_hi(hv.y), exj, acc[3]);
            acc[4] = fmaf(h2f_lo(hv.z), exj, acc[4]);
            acc[5] = fmaf(h2f_hi(hv.z), exj, acc[5]);
            acc[6] = fmaf(h2f_lo(hv.w), exj, acc[6]);
            acc[7] = fmaf(h2f_hi(hv.w), exj, acc[7]);
        }
    }

    #pragma unroll
    for (int off = LPE; off < 64; off <<= 1) {
        sacc += __shfl_xor(sacc, off);
        #pragma unroll
        for (int k = 0; k < CPL; k++) acc[k] += __shfl_xor(acc[k], off);
    }
    if (sub == 0) {
        float inv = 1.f / (sacc + 1e-16f);
        int ch = li * CPL;
        float r[CPL];
        #pragma unroll
        for (int k = 0; k < CPL; k++) {
            r[k] = acc[k] * inv + bias[ch + k];
            if (ELU_) r[k] = r[k] > 0.f ? r[k] : (__expf(r[k]) - 1.f);
        }
        if constexpr (OUTF16) {
            unsigned short* o = (unsigned short*)outv;
            unsigned int w0 = (unsigned int)f2h_bits(r[0]) | ((unsigned int)f2h_bits(r[1]) << 16);
            unsigned int w1 = (unsigned int)f2h_bits(r[2]) | ((unsigned int)f2h_bits(r[3]) << 16);
            unsigned int w2 = (unsigned int)f2h_bits(r[4]) | ((unsigned int)f2h_bits(r[5]) << 16);
            unsigned int w3 = (unsigned int)f2h_bits(r[6]) | ((unsigned int)f2h_bits(r[7]) << 16);
            uint4 q = { w0, w1, w2, w3 };
            *(uint4*)(void*)(o + (size_t)node * D + ch) = q;
        } else {
            float* o = (float*)outv;
            float4 w0 = { r[0], r[1], r[2], r[3] };
            float4 w1 = { r[4], r[5], r[6], r[7] };
            *(float4*)(o + (size_t)node * D + ch) = w0;
            *(float4*)(o + (size_t)node * D + ch + 4) = w1;
        }
    }
}

// ---------------------------------------------------------------------------
// Cooperative tail: agg1 -> gemm2 -> agg2 in one kernel (removes 2 gaps).
// waves_per_eu(2,4) pins the occupancy band so the allocator uses the full
// 128-VGPR budget instead of squeezing to 40 (R10 failure mode).
// ---------------------------------------------------------------------------
struct TailParams {
    const int* rowp; const int* colidx;
    const unsigned short* h1f16;
    const float* as1; const float* ad1; const float* bias1;
    unsigned short* hx16;
    const float* W2; const float* att_s2; const float* att_d2; const float* bias2;
    unsigned short* h2f16;
    float* as2; float* ad2;
    float* out;
    int N, nbagg, nbG2;
};

#define TAIL_SM 16640   // max(Bs NT=4: 16384 B, exs 4*4*65*8 = 8320 B)

__global__ __launch_bounds__(256)
__attribute__((amdgpu_waves_per_eu(2, 4)))
void tail_mega_kernel(TailParams p)
{
    __shared__ __align__(16) char sm[TAIL_SM];
    cg::grid_group grid = cg::this_grid();
    const int GB = (int)gridDim.x;

    // P3: layer-1 aggregate (4 nodes / virtual block)
    for (int vb = (int)blockIdx.x; vb < p.nbagg; vb += GB)
        agg_body<4, 32, true, true>((f2*)sm, vb, p.rowp, p.colidx, p.h1f16,
                                    p.as1, p.ad1, p.bias1, p.hx16, p.N);
    grid.sync();

    // P4: layer-2 gemm+attn (64 rows / virtual block)
    for (int vb = (int)blockIdx.x; vb < p.nbG2; vb += GB) {
        __syncthreads();   // protect Bs reuse across loop iterations
        gemm_attn_body<4, 1, true>((_Float16*)sm, vb, p.hx16, p.W2,
                                   p.att_s2, p.att_d2, p.h2f16, p.as2, p.ad2, p.N);
    }
    grid.sync();

    // P5: layer-2 aggregate -> fp32 out
    for (int vb = (int)blockIdx.x; vb < p.nbagg; vb += GB)
        agg_body<1, 64, false, false>((f2*)sm, vb, p.rowp, p.colidx, p.h2f16,
                                      p.as2, p.ad2, p.bias2, p.out, p.N);
}

// ---- non-cooperative fallbacks (same math; used only if coop launch fails) --
__global__ __launch_bounds__(256) void agg1_kernel(TailParams p)
{
    __shared__ __align__(16) char sm[8320];
    agg_body<4, 32, true, true>((f2*)sm, (int)blockIdx.x, p.rowp, p.colidx,
                                p.h1f16, p.as1, p.ad1, p.bias1, p.hx16, p.N);
}
__global__ __launch_bounds__(256) void gemm2_kernel(TailParams p)
{
    __shared__ _Float16 Bs[4 * 4 * 64 * 8];
    gemm_attn_body<4, 1, true>(Bs, (int)blockIdx.x, p.hx16, p.W2,
                               p.att_s2, p.att_d2, p.h2f16, p.as2, p.ad2, p.N);
}
__global__ __launch_bounds__(256) void agg2_kernel(TailParams p)
{
    __shared__ __align__(16) char sm[8320];
    agg_body<1, 64, false, false>((f2*)sm, (int)blockIdx.x, p.rowp, p.colidx,
                                  p.h2f16, p.as2, p.ad2, p.bias2, p.out, p.N);
}

// ---------------------------------------------------------------------------
extern "C" void kernel_launch(void* const* d_in, const int* in_sizes, int n_in,
                              void* d_out, int out_size, void* d_ws, size_t ws_size,
                              hipStream_t stream)
{
    const float* x        = (const float*)d_in[0];
    const int*   eidx     = (const int*)  d_in[1];
    const float* W1       = (const float*)d_in[2];
    const float* att_src1 = (const float*)d_in[3];
    const float* att_dst1 = (const float*)d_in[4];
    const float* bias1    = (const float*)d_in[5];
    const float* W2       = (const float*)d_in[6];
    const float* att_src2 = (const float*)d_in[7];
    const float* att_dst2 = (const float*)d_in[8];
    const float* bias2    = (const float*)d_in[9];
    float* out = (float*)d_out;

    const int N_ = in_sizes[0] / 128;
    const int E_ = in_sizes[1] / 2;
    const int ET = E_ + N_;
    const int NB = (N_ + 255) / 256;

    char* p = (char*)d_ws;
    auto alloc = [&](size_t bytes) {
        void* r = (void*)p;
        p += ((bytes + 255) / 256) * 256;
        return r;
    };
    int* rowp  = (int*)alloc((size_t)(N_ + 1) * 4);
    int* cfill = (int*)alloc((size_t)NB_BUCKETS * 4);
    int* colidx = (int*)alloc((size_t)ET * 4);
    unsigned int*   tmp   = (unsigned int*)alloc((size_t)NB_BUCKETS * BCAP * 4);
    // h1f16 must not alias tmp: gemm1 runs concurrently with splitA
    unsigned short* h1f16 = (unsigned short*)alloc((size_t)N_ * 128 * 2);
    unsigned short* hx16  = (unsigned short*)alloc((size_t)N_ * 128 * 2);
    unsigned short* h2f16 = (unsigned short*)alloc((size_t)N_ * 64 * 2);
    float* as1 = (float*)alloc((size_t)N_ * 4 * 4);
    float* ad1 = (float*)alloc((size_t)N_ * 4 * 4);
    float* as2 = (float*)alloc((size_t)N_ * 4);
    float* ad2 = (float*)alloc((size_t)N_ * 4);
    (void)ws_size; (void)n_in; (void)out_size;

    const int nbG = (N_ + 63) / 64;          // gemm blocks (782)
    const int nbA = (ET + 4095) / 4096;      // splitA blocks (403)

    // 1) zero bucket counters
    hipMemsetAsync(cfill, 0, (size_t)NB_BUCKETS * 4, stream);
    // 2) fat kernel: gemm_attn1 (MFMA) || splitA (LDS/mem) — independent
    build_and_gemm1_kernel<<<nbG + nbA, 256, 0, stream>>>(
        eidx, tmp, cfill, E_, ET, NB,
        x, W1, att_src1, att_dst1, h1f16, as1, ad1, N_, nbG);
    // 3) counting sort per bucket (inline scan) -> col + rowp
    passB_kernel<<<NB, 1024, 0, stream>>>(tmp, cfill, colidx, rowp, N_, NB, ET);

    // 4) cooperative tail: agg1 -> gemm2 -> agg2 (grid clamped by occupancy)
    TailParams tp;
    tp.rowp = rowp; tp.colidx = colidx;
    tp.h1f16 = h1f16; tp.as1 = as1; tp.ad1 = ad1; tp.bias1 = bias1;
    tp.hx16 = hx16;
    tp.W2 = W2; tp.att_s2 = att_src2; tp.att_d2 = att_dst2; tp.bias2 = bias2;
    tp.h2f16 = h2f16; tp.as2 = as2; tp.ad2 = ad2;
    tp.out = out;
    tp.N = N_;
    tp.nbagg = (N_ + 3) / 4;   // 12500
    tp.nbG2  = nbG;            // 782

    int occ = 0;
    hipError_t oerr = hipOccupancyMaxActiveBlocksPerMultiprocessor(
        &occ, (const void*)tail_mega_kernel, 256, 0);
    bool coop_ok = false;
    if (oerr == hipSuccess && occ > 0) {
        int grid = occ * 256;              // guaranteed co-resident on 256 CUs
        if (grid > 2048) grid = 2048;
        void* kargs[] = { &tp };
        hipError_t lerr = hipLaunchCooperativeKernel(
            (const void*)tail_mega_kernel, dim3(grid), dim3(256), kargs, 0, stream);
        coop_ok = (lerr == hipSuccess);
    }
    if (!coop_ok) {
        // deterministic fallback: identical math, three dispatches (R7 path)
        agg1_kernel<<<tp.nbagg, 256, 0, stream>>>(tp);
        gemm2_kernel<<<tp.nbG2, 256, 0, stream>>>(tp);
        agg2_kernel<<<tp.nbagg, 256, 0, stream>>>(tp);
    }
}